// Round 2
// baseline (236.272 us; speedup 1.0000x reference)
//
#include <hip/hip_runtime.h>

#define BB 1024
#define TT 1024
#define KQ 15
#define KT 20
#define NDOF 7

// Output layout (flat float offsets, in reference return order)
#define OFF_MODEL 0
#define OFF_QDL   1
#define OFF_QDDL  (1 + BB*NDOF)
#define OFF_QDDDL (1 + 2*BB*NDOF)
#define OFF_TQL   (1 + 3*BB*NDOF)
#define OFF_Q     (1 + 4*BB*NDOF)
#define OFF_QD    (OFF_Q    + (size_t)BB*TT*NDOF)
#define OFF_QDD   (OFF_QD   + (size_t)BB*TT*NDOF)
#define OFF_QDDD  (OFF_QDD  + (size_t)BB*TT*NDOF)
#define OFF_TQ    (OFF_QDDD + (size_t)BB*TT*NDOF)
#define OFF_T     (OFF_TQ   + (size_t)BB*TT*NDOF)
#define OFF_TCUM  (OFF_T    + (size_t)BB)
#define OFF_DT    (OFF_TCUM + (size_t)BB*TT)

__device__ __forceinline__ float hub(float v, float lim) {
    // huber(relu(|v| - lim)), delta = 1.0
    float x = fabsf(v) - lim;
    x = fmaxf(x, 0.0f);
    return (x < 1.0f) ? 0.5f * x * x : (x - 0.5f);
}

// 16B store at a 4B-aligned address (worked on this harness in the previous session)
__device__ __forceinline__ void st4(float* p, float x0, float x1, float x2, float x3) {
    float v[4] = {x0, x1, x2, x3};
    __builtin_memcpy(p, v, 16);
}

// 28B store (7 floats) at a 4B-aligned address: dwordx4 + dwordx2 + dword
__device__ __forceinline__ void st7(float* p, const float* a) {
    float v4[4] = {a[0], a[1], a[2], a[3]};
    __builtin_memcpy(p, v4, 16);
    float v2[2] = {a[4], a[5]};
    __builtin_memcpy(p + 4, v2, 8);
    p[6] = a[6];
}

// Fused: spline eval + derivatives + losses + dt + in-block cumsum (scan fused in).
// One block per b; 256 threads; thread handles t = r*256 + tid for r in [0,4).
// Basis matrices (480 KB total) are read directly from global (L1/L2-resident) —
// no LDS staging, no copy-out transpose. LDS = 4.5 KB (dt row + reduction scratch).
__global__ __launch_bounds__(256, 4) void feas_fused(
    const float* __restrict__ q_cps, const float* __restrict__ t_cps,
    const float* __restrict__ Nb,  const float* __restrict__ dNb,
    const float* __restrict__ ddNb, const float* __restrict__ dddNb,
    const float* __restrict__ Ntb, const float* __restrict__ dNtb,
    const float* __restrict__ ddNtb,
    const float* __restrict__ qd_lim, const float* __restrict__ qdd_lim,
    const float* __restrict__ qddd_lim,
    float* __restrict__ out, float* __restrict__ bsum)
{
    const int b    = blockIdx.x;
    const int tid  = threadIdx.x;
    const int lane = tid & 63;
    const int w    = tid >> 6;

    __shared__ __align__(16) float sdt[TT];   // dt row for the in-block scan
    __shared__ float wsum[4];                 // per-wave scan totals
    __shared__ float lossw[4][21];            // per-wave loss partials

    // whole block shares one b -> wave-uniform -> scalar loads
    const float* cps = q_cps + (size_t)b * (KQ * NDOF);
    const float* tcp = t_cps + (size_t)b * KT;

    // hoist time-spline control points into registers once
    float tcr[KT];
    #pragma unroll
    for (int k = 0; k < KT; ++k) tcr[k] = tcp[k];

    float ls[21];
    #pragma unroll
    for (int j = 0; j < 21; ++j) ls[j] = 0.f;

    // keep the round loop rolled: body is large; 4x unroll would blow I-cache
    #pragma unroll 1
    for (int r = 0; r < TT / 256; ++r) {
        const int t = r * 256 + tid;

        // ---- time-spline: 3 x 20 FMA, rows read straight from global (L2-hot) ----
        const float* pt0 = Ntb   + (size_t)t * KT;
        const float* pt1 = dNtb  + (size_t)t * KT;
        const float* pt2 = ddNtb + (size_t)t * KT;
        float dtau = 0.f, ddtau = 0.f, dddtau = 0.f;
        #pragma unroll
        for (int k = 0; k < KT; ++k) {
            const float tc = tcr[k];
            dtau   = fmaf(pt0[k], tc, dtau);
            ddtau  = fmaf(pt1[k], tc, ddtau);
            dddtau = fmaf(pt2[k], tc, dddtau);
        }

        // ---- q-spline: 4 x 15 x 7 FMA ----
        const float* p0 = Nb    + (size_t)t * KQ;
        const float* p1 = dNb   + (size_t)t * KQ;
        const float* p2 = ddNb  + (size_t)t * KQ;
        const float* p3 = dddNb + (size_t)t * KQ;
        float aq[NDOF], a1[NDOF], a2[NDOF], a3[NDOF];
        #pragma unroll
        for (int d = 0; d < NDOF; ++d) { aq[d] = 0.f; a1[d] = 0.f; a2[d] = 0.f; a3[d] = 0.f; }
        #pragma unroll
        for (int k = 0; k < KQ; ++k) {
            const float n0 = p0[k], n1 = p1[k], n2 = p2[k], n3 = p3[k];
            #pragma unroll
            for (int d = 0; d < NDOF; ++d) {
                const float cc = cps[k * NDOF + d];   // uniform -> s_load
                aq[d] = fmaf(n0, cc, aq[d]);
                a1[d] = fmaf(n1, cc, a1[d]);
                a2[d] = fmaf(n2, cc, a2[d]);
                a3[d] = fmaf(n3, cc, a3[d]);
            }
        }

        const float dtau2 = dtau * dtau;
        const float dtau3 = dtau2 * dtau;
        const float dtv   = 1.0f / (dtau * (float)TT);

        float qd[NDOF], qdd[NDOF], qddd[NDOF];
        #pragma unroll
        for (int d = 0; d < NDOF; ++d) {
            qd[d]   = a1[d] * dtau;
            qdd[d]  = a2[d] * dtau2 + ddtau * a1[d] * dtau;
            qddd[d] = a3[d] * dtau3 + 3.0f * a2[d] * ddtau * dtau2
                    + a1[d] * dtau2 * dddtau + a1[d] * ddtau * ddtau * dtau;
        }

        // ---- loss partials accumulate in registers across rounds ----
        #pragma unroll
        for (int d = 0; d < NDOF; ++d) {
            ls[d]          += hub(qd[d],   qd_lim[d])   * dtv;
            ls[NDOF + d]   += hub(qdd[d],  qdd_lim[d])  * dtv;
            ls[2*NDOF + d] += hub(qddd[d], qddd_lim[d]) * dtv;
        }

        // ---- direct stores: per-lane 28B, wave covers a dense 1792B run ----
        const size_t gb = (size_t)b * (TT * NDOF) + (size_t)t * NDOF;
        st7(out + OFF_Q    + gb, aq);
        st7(out + OFF_QD   + gb, qd);
        st7(out + OFF_QDD  + gb, qdd);
        st7(out + OFF_QDDD + gb, qddd);
        {   // torque == 0: literal zero stores (no stack array)
            float* z = out + OFF_TQ + gb;
            st4(z, 0.f, 0.f, 0.f, 0.f);
            float v2[2] = {0.f, 0.f};
            __builtin_memcpy(z + 4, v2, 8);
            z[6] = 0.f;
        }
        out[OFF_DT + (size_t)b * TT + t] = dtv;   // coalesced dword
        sdt[t] = dtv;
    }

    __syncthreads();

    // ---- in-block inclusive scan of sdt (replaces the old feas_scan kernel) ----
    const int s4 = 4 * tid;
    const float4 dvv = *(const float4*)(sdt + s4);   // 16B-aligned
    const float c0 = dvv.x;
    const float c1 = c0 + dvv.y;
    const float c2 = c1 + dvv.z;
    const float c3 = c2 + dvv.w;
    float s = c3;
    #pragma unroll
    for (int off = 1; off < 64; off <<= 1) {
        const float u = __shfl_up(s, off);
        if (lane >= off) s += u;
    }
    if (lane == 63) wsum[w] = s;   // inclusive wave total

    // ---- wave loss reduce (proven shfl_down path; now once per kernel) ----
    #pragma unroll
    for (int j = 0; j < 21; ++j) {
        float v = ls[j];
        #pragma unroll
        for (int off = 32; off > 0; off >>= 1) v += __shfl_down(v, off);
        ls[j] = v;   // valid at lane 0
    }
    if (lane == 0) {
        #pragma unroll
        for (int j = 0; j < 21; ++j) lossw[w][j] = ls[j];
    }

    __syncthreads();

    // cross-wave scan offset + t_cumsum stores
    float woff = 0.f;
    #pragma unroll
    for (int i = 0; i < 4; ++i) if (i < w) woff += wsum[i];
    const float excl = woff + (s - c3);   // exclusive prefix before this thread's 4 elems
    st4(out + OFF_TCUM + (size_t)b * TT + s4,
        c0 + excl, c1 + excl, c2 + excl, c3 + excl);

    // loss finalize
    if (tid < 21) {
        const float acc = lossw[0][tid] + lossw[1][tid] + lossw[2][tid] + lossw[3][tid];
        const int which = tid / NDOF, d = tid - which * NDOF;
        const size_t o = (which == 0) ? (size_t)OFF_QDL
                       : (which == 1) ? (size_t)OFF_QDDL : (size_t)OFF_QDDDL;
        out[o + (size_t)b * NDOF + d] = acc;
    }
    if (tid < NDOF) out[OFF_TQL + (size_t)b * NDOF + tid] = 0.0f;  // torque == 0
    if (tid == 0) {
        out[OFF_T + b] = wsum[0] + wsum[1] + wsum[2] + wsum[3];
        float p = 0.f;
        #pragma unroll
        for (int i = 0; i < 4; ++i) {
            #pragma unroll
            for (int j = 0; j < 21; ++j) p += lossw[i][j];
        }
        bsum[b] = p;   // per-b model partial (no atomics)
    }
}

// single block: model_loss = sum of 1024 per-b partials
__global__ __launch_bounds__(256) void feas_final(
    const float* __restrict__ bsum, float* __restrict__ out)
{
    __shared__ float wsums[4];
    const int tid  = threadIdx.x;
    const int lane = tid & 63;
    const int w    = tid >> 6;
    float v = 0.f;
    #pragma unroll
    for (int j = 0; j < 4; ++j) v += bsum[j * 256 + tid];
    #pragma unroll
    for (int off = 32; off > 0; off >>= 1) v += __shfl_down(v, off);
    if (lane == 0) wsums[w] = v;
    __syncthreads();
    if (tid == 0) out[OFF_MODEL] = wsums[0] + wsums[1] + wsums[2] + wsums[3];
}

extern "C" void kernel_launch(void* const* d_in, const int* in_sizes, int n_in,
                              void* d_out, int out_size, void* d_ws, size_t ws_size,
                              hipStream_t stream) {
    const float* q_cps    = (const float*)d_in[0];
    const float* t_cps    = (const float*)d_in[1];
    const float* Nb       = (const float*)d_in[2];
    const float* dNb      = (const float*)d_in[3];
    const float* ddNb     = (const float*)d_in[4];
    const float* dddNb    = (const float*)d_in[5];
    const float* Ntb      = (const float*)d_in[6];
    const float* dNtb     = (const float*)d_in[7];
    const float* ddNtb    = (const float*)d_in[8];
    const float* qd_lim   = (const float*)d_in[9];
    const float* qdd_lim  = (const float*)d_in[10];
    const float* qddd_lim = (const float*)d_in[11];
    // d_in[12] = torque_limits — unused (torque is identically zero)
    float* out  = (float*)d_out;
    float* bsum = (float*)d_ws;   // 1024 floats

    feas_fused<<<dim3(BB), dim3(256), 0, stream>>>(
        q_cps, t_cps, Nb, dNb, ddNb, dddNb, Ntb, dNtb, ddNtb,
        qd_lim, qdd_lim, qddd_lim, out, bsum);
    feas_final<<<dim3(1), dim3(256), 0, stream>>>(bsum, out);
}